// Round 1
// baseline (480.001 us; speedup 1.0000x reference)
//
#include <hip/hip_runtime.h>

#define D 128
#define G_GRAPHS 512

typedef _Float16 f16;
typedef _Float16 f16x8 __attribute__((ext_vector_type(8)));
typedef float f32x4 __attribute__((ext_vector_type(4)));

// ---------------------------------------------------------------- degrees
__global__ void degree_kernel(const int* __restrict__ src, const int* __restrict__ dst,
                              int* __restrict__ deg_out, int* __restrict__ deg_in, int E) {
    int e = blockIdx.x * 256 + threadIdx.x;
    if (e < E) {
        atomicAdd(&deg_out[src[e]], 1);
        atomicAdd(&deg_in[dst[e]], 1);
    }
}

__global__ void norm_kernel(const int* __restrict__ deg_out, const int* __restrict__ deg_in,
                            float* __restrict__ norm_src, float* __restrict__ norm_dst, int N) {
    int n = blockIdx.x * 256 + threadIdx.x;
    if (n < N) {
        norm_src[n] = rsqrtf(fmaxf((float)deg_out[n], 1.0f));
        norm_dst[n] = rsqrtf(fmaxf((float)deg_in[n], 1.0f));
    }
}

// ---------------------------------------------------------------- exclusive scan (1 block)
__global__ __launch_bounds__(1024) void scan_kernel(const int* __restrict__ deg,
                                                    int* __restrict__ offsets,
                                                    int* __restrict__ cursor, int n) {
    __shared__ int wsum[16];
    __shared__ int carry_s;
    int lane = threadIdx.x & 63;
    int wid  = threadIdx.x >> 6;
    if (threadIdx.x == 0) carry_s = 0;
    __syncthreads();
    for (int base = 0; base < n; base += 1024) {
        int i = base + (int)threadIdx.x;
        int v = (i < n) ? deg[i] : 0;
        int s = v;
        #pragma unroll
        for (int off = 1; off < 64; off <<= 1) {
            int t = __shfl_up(s, off);
            if (lane >= off) s += t;
        }
        if (lane == 63) wsum[wid] = s;
        __syncthreads();
        if (threadIdx.x < 16) {
            int ws2 = wsum[threadIdx.x];
            #pragma unroll
            for (int off = 1; off < 16; off <<= 1) {
                int t = __shfl_up(ws2, off);
                if (lane >= off) ws2 += t;
            }
            wsum[threadIdx.x] = ws2;
        }
        __syncthreads();
        int waveoff = wid ? wsum[wid - 1] : 0;
        int c = carry_s;
        int excl = c + waveoff + s - v;
        if (i < n) { offsets[i] = excl; cursor[i] = excl; }
        __syncthreads();
        if (threadIdx.x == 0) carry_s = c + wsum[15];
        __syncthreads();
    }
    if (threadIdx.x == 0) offsets[n] = carry_s;
}

// ---------------------------------------------------------------- CSR fill (order within bucket arbitrary)
__global__ void fill_kernel(const int* __restrict__ src, const int* __restrict__ dst,
                            int* __restrict__ cursor, int* __restrict__ csr_src, int E) {
    int e = blockIdx.x * 256 + threadIdx.x;
    if (e < E) {
        int p = atomicAdd(&cursor[dst[e]], 1);
        csr_src[p] = src[e];
    }
}

// ---------------------------------------------------------------- gather: A[n] = f16(norm_dst[n] * sum_{s in in(n)} x[s]*norm_src[s])
template <typename InT>
__global__ void gather_kernel(const InT* __restrict__ x,
                              const float* __restrict__ norm_src, const float* __restrict__ norm_dst,
                              const int* __restrict__ offsets, const int* __restrict__ csr_src,
                              f16* __restrict__ A, int N) {
    int half = threadIdx.x >> 7;          // 2 nodes per 256-thread block
    int lane = threadIdx.x & 127;         // feature dim
    int node = blockIdx.x * 2 + half;
    if (node >= N) return;
    int beg = offsets[node], end = offsets[node + 1];
    float a0 = 0.f, a1 = 0.f, a2 = 0.f, a3 = 0.f;
    int e = beg;
    for (; e + 4 <= end; e += 4) {
        int s0 = csr_src[e], s1 = csr_src[e + 1], s2 = csr_src[e + 2], s3 = csr_src[e + 3];
        float n0 = norm_src[s0], n1 = norm_src[s1], n2 = norm_src[s2], n3 = norm_src[s3];
        a0 += (float)x[s0 * D + lane] * n0;
        a1 += (float)x[s1 * D + lane] * n1;
        a2 += (float)x[s2 * D + lane] * n2;
        a3 += (float)x[s3 * D + lane] * n3;
    }
    for (; e < end; ++e) {
        int s = csr_src[e];
        a0 += (float)x[s * D + lane] * norm_src[s];
    }
    float v = ((a0 + a1) + (a2 + a3)) * norm_dst[node];
    A[node * D + lane] = (f16)v;
}

// ---------------------------------------------------------------- GEMM: out = relu(A[M,128] @ W[128,128] + b), f16 MFMA
// W packed in LDS in fragment order: frag (t=kstep, c=coltile): lane l holds
// W[k = t*32 + 8*(l>>4) + b][j = c*16 + (l&15)], b=0..7 contiguous -> ds_read_b128.
template <typename OutT>
__global__ __launch_bounds__(256) void gemm_kernel(const f16* __restrict__ A,
                                                   const float* __restrict__ Wg,
                                                   const float* __restrict__ bias,
                                                   OutT* __restrict__ out, int M) {
    __shared__ f16 Wf[4 * 8 * 64 * 8];   // 32 KiB
    for (int i = threadIdx.x; i < D * D; i += 256) {
        int k = i >> 7, j = i & 127;
        int t = k >> 5, c = j >> 4;
        int l = ((k & 31) >> 3) * 16 + (j & 15);
        int b = k & 7;
        Wf[((t * 8 + c) * 64 + l) * 8 + b] = (f16)Wg[i];
    }
    __syncthreads();
    int wave = threadIdx.x >> 6, lane = threadIdx.x & 63;

    for (int row0 = (blockIdx.x * 4 + wave) * 16; row0 < M; row0 += gridDim.x * 64) {
        int arow = row0 + (lane & 15);
        const f16* Abase = A + arow * D + (lane >> 4) * 8;
        f16x8 a[4];
        #pragma unroll
        for (int t = 0; t < 4; ++t) a[t] = *(const f16x8*)(Abase + t * 32);

        #pragma unroll
        for (int c = 0; c < 8; ++c) {
            f32x4 acc = {0.f, 0.f, 0.f, 0.f};
            #pragma unroll
            for (int t = 0; t < 4; ++t) {
                f16x8 bf = *(const f16x8*)&Wf[((t * 8 + c) * 64 + lane) * 8];
                acc = __builtin_amdgcn_mfma_f32_16x16x32_f16(a[t], bf, acc, 0, 0, 0);
            }
            int col = c * 16 + (lane & 15);
            float bj = bias[col];
            #pragma unroll
            for (int r = 0; r < 4; ++r) {
                int row = row0 + (lane >> 4) * 4 + r;
                float v = fmaxf(acc[r] + bj, 0.f);
                out[row * D + col] = (OutT)v;
            }
        }
    }
}

// ---------------------------------------------------------------- gate[n] = sigmoid(dot(h[n], wg) + bg)
__global__ void gate_kernel(const float* __restrict__ h, const float* __restrict__ wg,
                            const float* __restrict__ bg, float* __restrict__ gate, int N) {
    int node = blockIdx.x * 4 + (threadIdx.x >> 6);
    int lane = threadIdx.x & 63;
    if (node >= N) return;
    const float* row = h + node * D;
    float s = row[lane] * wg[lane] + row[lane + 64] * wg[lane + 64];
    #pragma unroll
    for (int off = 32; off; off >>= 1) s += __shfl_down(s, off);
    if (lane == 0) gate[node] = 1.0f / (1.0f + __expf(-(s + bg[0])));
}

// ---------------------------------------------------------------- graph ranges (graph_ids sorted)
__global__ void gstart_kernel(const int* __restrict__ gid, int* __restrict__ gstart, int N, int G) {
    int n = blockIdx.x * 256 + threadIdx.x;
    if (n >= N) return;
    int g = gid[n];
    if (n == 0) {
        for (int x = 0; x <= g; ++x) gstart[x] = 0;
    } else {
        int pg = gid[n - 1];
        for (int x = pg + 1; x <= g; ++x) gstart[x] = n;
    }
    if (n == N - 1) {
        for (int x = g + 1; x <= G; ++x) gstart[x] = N;
    }
}

// ---------------------------------------------------------------- wh[g] = sum_{n in graph g} gate[n]*h[n]
__global__ void gagg_kernel(const float* __restrict__ h, const float* __restrict__ gate,
                            const int* __restrict__ gstart, float* __restrict__ wh) {
    __shared__ float part[D];
    int g = blockIdx.x;
    int half = threadIdx.x >> 7, d = threadIdx.x & 127;
    int beg = gstart[g], end = gstart[g + 1];
    float s = 0.f;
    for (int n = beg + half; n < end; n += 2) s += gate[n] * h[n * D + d];
    if (half) part[d] = s;
    __syncthreads();
    if (!half) wh[g * D + d] = s + part[d];
}

// ---------------------------------------------------------------- launch
extern "C" void kernel_launch(void* const* d_in, const int* in_sizes, int n_in,
                              void* d_out, int out_size, void* d_ws, size_t ws_size,
                              hipStream_t stream) {
    const int*   src  = (const int*)d_in[0];
    const int*   dst  = (const int*)d_in[1];
    const int*   gid  = (const int*)d_in[2];
    const float* feat = (const float*)d_in[3];
    const float* w1   = (const float*)d_in[4];
    const float* b1   = (const float*)d_in[5];
    const float* w2   = (const float*)d_in[6];
    const float* b2   = (const float*)d_in[7];
    const float* wg   = (const float*)d_in[8];
    const float* bg   = (const float*)d_in[9];
    int E = in_sizes[0];
    int N = in_sizes[2];
    const int G = G_GRAPHS;

    char* ws = (char*)d_ws;
    size_t off = 0;
    auto carve = [&](size_t bytes) { void* p = ws + off; off = (off + bytes + 255) & ~(size_t)255; return p; };
    int*   deg_out_i = (int*)  carve((size_t)N * 4);
    int*   deg_in_i  = (int*)  carve((size_t)N * 4);
    float* norm_src  = (float*)carve((size_t)N * 4);
    float* norm_dst  = (float*)carve((size_t)N * 4);
    int*   offsets   = (int*)  carve((size_t)(N + 1) * 4);
    int*   cursor    = (int*)  carve((size_t)N * 4);
    int*   csr_src   = (int*)  carve((size_t)E * 4);
    f16*   A         = (f16*)  carve((size_t)N * D * 2);
    f16*   h1        = (f16*)  carve((size_t)N * D * 2);
    float* gate      = (float*)carve((size_t)N * 4);
    int*   gstart    = (int*)  carve((size_t)(G + 1) * 4);

    float* wh_out = (float*)d_out;              // [512, 128]
    float* h_out  = (float*)d_out + (size_t)G * D;  // [N, 128]

    // degree arrays are adjacent at ws start: one memset covers both
    hipMemsetAsync(deg_out_i, 0, (size_t)2 * ((size_t)N * 4 + 255 & ~(size_t)255), stream);

    degree_kernel<<<(E + 255) / 256, 256, 0, stream>>>(src, dst, deg_out_i, deg_in_i, E);
    norm_kernel<<<(N + 255) / 256, 256, 0, stream>>>(deg_out_i, deg_in_i, norm_src, norm_dst, N);
    scan_kernel<<<1, 1024, 0, stream>>>(deg_in_i, offsets, cursor, N);
    fill_kernel<<<(E + 255) / 256, 256, 0, stream>>>(src, dst, cursor, csr_src, E);

    gather_kernel<float><<<(N + 1) / 2, 256, 0, stream>>>(feat, norm_src, norm_dst, offsets, csr_src, A, N);
    gemm_kernel<f16><<<512, 256, 0, stream>>>(A, w1, b1, h1, N);
    gather_kernel<f16><<<(N + 1) / 2, 256, 0, stream>>>(h1, norm_src, norm_dst, offsets, csr_src, A, N);
    gemm_kernel<float><<<512, 256, 0, stream>>>(A, w2, b2, h_out, N);

    gate_kernel<<<(N + 3) / 4, 256, 0, stream>>>(h_out, wg, bg, gate, N);
    gstart_kernel<<<(N + 255) / 256, 256, 0, stream>>>(gid, gstart, N, G);
    gagg_kernel<<<G, 256, 0, stream>>>(h_out, gate, gstart, wh_out);
}

// Round 2
// 265.288 us; speedup vs baseline: 1.8094x; 1.8094x over previous
//
#include <hip/hip_runtime.h>

#define D 128
#define G_GRAPHS 512

typedef _Float16 f16;
typedef _Float16 f16x2 __attribute__((ext_vector_type(2)));
typedef _Float16 f16x4 __attribute__((ext_vector_type(4)));
typedef _Float16 f16x8 __attribute__((ext_vector_type(8)));
typedef float f32x4 __attribute__((ext_vector_type(4)));

#define SCAN_CHUNK 2048   // 256 threads x 8 elems

// ---------------------------------------------------------------- degrees
__global__ void degree_kernel(const int* __restrict__ src, const int* __restrict__ dst,
                              int* __restrict__ deg_out, int* __restrict__ deg_in, int E) {
    int e = blockIdx.x * 256 + threadIdx.x;
    if (e < E) {
        atomicAdd(&deg_out[src[e]], 1);
        atomicAdd(&deg_in[dst[e]], 1);
    }
}

__global__ void norm_kernel(const int* __restrict__ deg_out, const int* __restrict__ deg_in,
                            float* __restrict__ norm_src, float* __restrict__ norm_dst, int N) {
    int n = blockIdx.x * 256 + threadIdx.x;
    if (n < N) {
        norm_src[n] = rsqrtf(fmaxf((float)deg_out[n], 1.0f));
        norm_dst[n] = rsqrtf(fmaxf((float)deg_in[n], 1.0f));
    }
}

// ---------------------------------------------------------------- prescale: Xn = f16(feat * norm_src[row])
__global__ void prescale_kernel(const float* __restrict__ feat, const float* __restrict__ ns,
                                f16x4* __restrict__ out, int count /* N*32 */) {
    int i = blockIdx.x * 256 + threadIdx.x;
    if (i >= count) return;
    float4 v = ((const float4*)feat)[i];
    float s = ns[i >> 5];
    f16x4 o = { (f16)(v.x * s), (f16)(v.y * s), (f16)(v.z * s), (f16)(v.w * s) };
    out[i] = o;
}

// ---------------------------------------------------------------- hierarchical scan
__global__ __launch_bounds__(256) void scan1_kernel(const int* __restrict__ deg,
                                                    int* __restrict__ partial,
                                                    int* __restrict__ blocksums, int n) {
    __shared__ int wsum[4];
    int lane = threadIdx.x & 63, wid = threadIdx.x >> 6;
    int base = blockIdx.x * SCAN_CHUNK + (int)threadIdx.x * 8;
    int v[8]; int tsum = 0;
    #pragma unroll
    for (int i = 0; i < 8; ++i) { v[i] = (base + i < n) ? deg[base + i] : 0; tsum += v[i]; }
    int s = tsum;
    #pragma unroll
    for (int off = 1; off < 64; off <<= 1) {
        int t = __shfl_up(s, off);
        if (lane >= off) s += t;
    }
    if (lane == 63) wsum[wid] = s;
    __syncthreads();
    int woff = 0;
    for (int w = 0; w < wid; ++w) woff += wsum[w];
    int run = woff + s - tsum;
    #pragma unroll
    for (int i = 0; i < 8; ++i) {
        if (base + i < n) partial[base + i] = run;
        run += v[i];
    }
    if (threadIdx.x == 255) blocksums[blockIdx.x] = woff + s;
}

__global__ void scan2_kernel(int* __restrict__ bs, int* __restrict__ total_out, int nb) {
    int lane = threadIdx.x;  // 64 threads, 1 wave
    int carry = 0;
    for (int base = 0; base < nb; base += 64) {
        int i = base + lane;
        int v = (i < nb) ? bs[i] : 0;
        int s = v;
        #pragma unroll
        for (int off = 1; off < 64; off <<= 1) {
            int t = __shfl_up(s, off);
            if (lane >= off) s += t;
        }
        if (i < nb) bs[i] = carry + s - v;
        carry += __shfl(s, 63);
    }
    if (lane == 0) *total_out = carry;
}

__global__ void scan3_kernel(int* __restrict__ offsets, const int* __restrict__ bs,
                             int* __restrict__ cursor, int n) {
    int i = blockIdx.x * 256 + threadIdx.x;
    if (i >= n) return;
    int v = offsets[i] + bs[i >> 11];   // SCAN_CHUNK = 2048
    offsets[i] = v;
    cursor[i] = v;
}

// ---------------------------------------------------------------- CSR fill
__global__ void fill_kernel(const int* __restrict__ src, const int* __restrict__ dst,
                            int* __restrict__ cursor, int* __restrict__ csr_src, int E) {
    int e = blockIdx.x * 256 + threadIdx.x;
    if (e < E) {
        int p = atomicAdd(&cursor[dst[e]], 1);
        csr_src[p] = src[e];
    }
}

// ---------------------------------------------------------------- gather: A[n] = f16(norm_dst[n] * sum_{s in in(n)} x[s])
// x is pre-scaled by norm_src. 1 wave per node, 64 lanes x f16x2.
__global__ __launch_bounds__(256) void gather_kernel(const f16* __restrict__ x,
                                                     const float* __restrict__ norm_dst,
                                                     const int* __restrict__ offsets,
                                                     const int* __restrict__ csr_src,
                                                     f16* __restrict__ A, int N) {
    int node = __builtin_amdgcn_readfirstlane(blockIdx.x * 4 + ((int)threadIdx.x >> 6));
    int lane = threadIdx.x & 63;
    if (node >= N) return;
    int beg = offsets[node], end = offsets[node + 1];
    const f16x2* x2 = (const f16x2*)x;
    float a0 = 0.f, b0 = 0.f, a1 = 0.f, b1 = 0.f, a2 = 0.f, b2 = 0.f, a3 = 0.f, b3 = 0.f;
    int e = beg;
    for (; e + 4 <= end; e += 4) {
        int s0 = csr_src[e], s1 = csr_src[e + 1], s2 = csr_src[e + 2], s3 = csr_src[e + 3];
        f16x2 v0 = x2[s0 * 64 + lane];
        f16x2 v1 = x2[s1 * 64 + lane];
        f16x2 v2 = x2[s2 * 64 + lane];
        f16x2 v3 = x2[s3 * 64 + lane];
        a0 += (float)v0.x; b0 += (float)v0.y;
        a1 += (float)v1.x; b1 += (float)v1.y;
        a2 += (float)v2.x; b2 += (float)v2.y;
        a3 += (float)v3.x; b3 += (float)v3.y;
    }
    for (; e < end; ++e) {
        int s = csr_src[e];
        f16x2 v = x2[s * 64 + lane];
        a0 += (float)v.x; b0 += (float)v.y;
    }
    float nd = norm_dst[node];
    float ox = ((a0 + a1) + (a2 + a3)) * nd;
    float oy = ((b0 + b1) + (b2 + b3)) * nd;
    f16x2 o; o.x = (f16)ox; o.y = (f16)oy;
    ((f16x2*)A)[node * 64 + lane] = o;
}

// ---------------------------------------------------------------- GEMM: out = relu(A[M,128] @ W[128,128] + b) [* rowscale] [+ gate]
// W packed in LDS fragment order: lane l holds W[k = t*32 + 8*(l>>4) + b][j = c*16 + (l&15)].
template <typename OutT, bool SCALE, bool GATE>
__global__ __launch_bounds__(256) void gemm_kernel(const f16* __restrict__ A,
                                                   const float* __restrict__ Wg,
                                                   const float* __restrict__ bias,
                                                   const float* __restrict__ rowscale,
                                                   const float* __restrict__ wgv,
                                                   const float* __restrict__ bgv,
                                                   float* __restrict__ gate_out,
                                                   OutT* __restrict__ out, int M) {
    __shared__ f16 Wf[4 * 8 * 64 * 8];   // 32 KiB
    for (int i = threadIdx.x; i < 2048; i += 256) {   // i = kg*128 + j
        int kg = i >> 7, j = i & 127;
        int k0 = kg * 8;
        f16x8 tmp;
        #pragma unroll
        for (int b = 0; b < 8; ++b) tmp[b] = (f16)Wg[(k0 + b) * D + j];
        int t = k0 >> 5, c = j >> 4;
        int l = ((k0 & 31) >> 3) * 16 + (j & 15);
        *(f16x8*)&Wf[((t * 8 + c) * 64 + l) * 8] = tmp;
    }
    __syncthreads();
    int wave = threadIdx.x >> 6, lane = threadIdx.x & 63;

    for (int row0 = (blockIdx.x * 4 + wave) * 16; row0 < M; row0 += gridDim.x * 64) {
        int arow = row0 + (lane & 15);
        const f16* Abase = A + arow * D + (lane >> 4) * 8;
        f16x8 a[4];
        #pragma unroll
        for (int t = 0; t < 4; ++t) a[t] = *(const f16x8*)(Abase + t * 32);

        float ns[4];
        if (SCALE) {
            #pragma unroll
            for (int r = 0; r < 4; ++r) ns[r] = rowscale[row0 + (lane >> 4) * 4 + r];
        }
        float dotr[4] = {0.f, 0.f, 0.f, 0.f};

        #pragma unroll
        for (int c = 0; c < 8; ++c) {
            f32x4 acc = {0.f, 0.f, 0.f, 0.f};
            #pragma unroll
            for (int t = 0; t < 4; ++t) {
                f16x8 bf = *(const f16x8*)&Wf[((t * 8 + c) * 64 + lane) * 8];
                acc = __builtin_amdgcn_mfma_f32_16x16x32_f16(a[t], bf, acc, 0, 0, 0);
            }
            int col = c * 16 + (lane & 15);
            float bj = bias[col];
            float wgc = GATE ? wgv[col] : 0.f;
            #pragma unroll
            for (int r = 0; r < 4; ++r) {
                int row = row0 + (lane >> 4) * 4 + r;
                float v = fmaxf(acc[r] + bj, 0.f);
                if (SCALE) v *= ns[r];
                out[row * D + col] = (OutT)v;
                if (GATE) dotr[r] += v * wgc;
            }
        }
        if (GATE) {
            float bg0 = bgv[0];
            #pragma unroll
            for (int r = 0; r < 4; ++r) {
                float d = dotr[r];
                d += __shfl_xor(d, 1); d += __shfl_xor(d, 2);
                d += __shfl_xor(d, 4); d += __shfl_xor(d, 8);
                if ((lane & 15) == 0)
                    gate_out[row0 + (lane >> 4) * 4 + r] = 1.0f / (1.0f + __expf(-(d + bg0)));
            }
        }
    }
}

// ---------------------------------------------------------------- graph ranges (graph_ids sorted)
__global__ void gstart_kernel(const int* __restrict__ gid, int* __restrict__ gstart, int N, int G) {
    int n = blockIdx.x * 256 + threadIdx.x;
    if (n >= N) return;
    int g = gid[n];
    if (n == 0) {
        for (int x = 0; x <= g; ++x) gstart[x] = 0;
    } else {
        int pg = gid[n - 1];
        for (int x = pg + 1; x <= g; ++x) gstart[x] = n;
    }
    if (n == N - 1) {
        for (int x = g + 1; x <= G; ++x) gstart[x] = N;
    }
}

// ---------------------------------------------------------------- wh[g] = sum_{n in graph g} gate[n]*h[n]
__global__ __launch_bounds__(256) void gagg_kernel(const float* __restrict__ h,
                                                   const float* __restrict__ gate,
                                                   const int* __restrict__ gstart,
                                                   float* __restrict__ wh) {
    __shared__ float part[4][D];
    int g = blockIdx.x;
    int wave = threadIdx.x >> 6, lane = threadIdx.x & 63;
    int beg = gstart[g], end = gstart[g + 1];
    float2 acc = {0.f, 0.f};
    for (int n = beg + wave; n < end; n += 4) {
        float gv = gate[n];
        float2 hv = ((const float2*)(h + n * D))[lane];
        acc.x += gv * hv.x;
        acc.y += gv * hv.y;
    }
    part[wave][lane * 2]     = acc.x;
    part[wave][lane * 2 + 1] = acc.y;
    __syncthreads();
    if (wave == 0) {
        float sx = 0.f, sy = 0.f;
        #pragma unroll
        for (int w = 0; w < 4; ++w) { sx += part[w][lane * 2]; sy += part[w][lane * 2 + 1]; }
        float2 o = {sx, sy};
        ((float2*)(wh + g * D))[lane] = o;
    }
}

// ---------------------------------------------------------------- launch
extern "C" void kernel_launch(void* const* d_in, const int* in_sizes, int n_in,
                              void* d_out, int out_size, void* d_ws, size_t ws_size,
                              hipStream_t stream) {
    const int*   src  = (const int*)d_in[0];
    const int*   dst  = (const int*)d_in[1];
    const int*   gid  = (const int*)d_in[2];
    const float* feat = (const float*)d_in[3];
    const float* w1   = (const float*)d_in[4];
    const float* b1   = (const float*)d_in[5];
    const float* w2   = (const float*)d_in[6];
    const float* b2   = (const float*)d_in[7];
    const float* wg   = (const float*)d_in[8];
    const float* bg   = (const float*)d_in[9];
    int E = in_sizes[0];
    int N = in_sizes[2];
    const int G = G_GRAPHS;

    char* ws = (char*)d_ws;
    size_t off = 0;
    auto carve = [&](size_t bytes) { void* p = ws + off; off = (off + bytes + 255) & ~(size_t)255; return p; };
    int*   deg_out_i = (int*)  carve((size_t)N * 4);
    int*   deg_in_i  = (int*)  carve((size_t)N * 4);
    float* norm_src  = (float*)carve((size_t)N * 4);
    float* norm_dst  = (float*)carve((size_t)N * 4);
    int*   offsets   = (int*)  carve((size_t)(N + 1) * 4);
    int*   cursor    = (int*)  carve((size_t)N * 4);
    int*   blocksums = (int*)  carve((size_t)64 * 4);
    int*   csr_src   = (int*)  carve((size_t)E * 4);
    f16*   Xh        = (f16*)  carve((size_t)N * D * 2);  // Xn for layer1, then h1*norm_src
    f16*   A         = (f16*)  carve((size_t)N * D * 2);
    float* gate      = (float*)carve((size_t)N * 4);
    int*   gstart    = (int*)  carve((size_t)(G + 1) * 4);

    float* wh_out = (float*)d_out;                  // [512, 128]
    float* h_out  = (float*)d_out + (size_t)G * D;  // [N, 128]

    int nb = (N + SCAN_CHUNK - 1) / SCAN_CHUNK;     // 49 blocks for N=100000

    hipMemsetAsync(deg_out_i, 0, (size_t)N * 4, stream);
    hipMemsetAsync(deg_in_i, 0, (size_t)N * 4, stream);

    degree_kernel<<<(E + 255) / 256, 256, 0, stream>>>(src, dst, deg_out_i, deg_in_i, E);
    norm_kernel<<<(N + 255) / 256, 256, 0, stream>>>(deg_out_i, deg_in_i, norm_src, norm_dst, N);
    prescale_kernel<<<(N * 32 + 255) / 256, 256, 0, stream>>>(feat, norm_src, (f16x4*)Xh, N * 32);

    scan1_kernel<<<nb, 256, 0, stream>>>(deg_in_i, offsets, blocksums, N);
    scan2_kernel<<<1, 64, 0, stream>>>(blocksums, offsets + N, nb);
    scan3_kernel<<<(N + 255) / 256, 256, 0, stream>>>(offsets, blocksums, cursor, N);
    fill_kernel<<<(E + 255) / 256, 256, 0, stream>>>(src, dst, cursor, csr_src, E);

    // layer 1
    gather_kernel<<<(N + 3) / 4, 256, 0, stream>>>(Xh, norm_dst, offsets, csr_src, A, N);
    gemm_kernel<f16, true, false><<<512, 256, 0, stream>>>(A, w1, b1, norm_src, nullptr, nullptr, nullptr, Xh, N);
    // layer 2
    gather_kernel<<<(N + 3) / 4, 256, 0, stream>>>(Xh, norm_dst, offsets, csr_src, A, N);
    gemm_kernel<float, false, true><<<512, 256, 0, stream>>>(A, w2, b2, nullptr, wg, bg, gate, h_out, N);

    gstart_kernel<<<(N + 255) / 256, 256, 0, stream>>>(gid, gstart, N, G);
    gagg_kernel<<<G, 256, 0, stream>>>(h_out, gate, gstart, wh_out);
}